// Round 2
// baseline (835.550 us; speedup 1.0000x reference)
//
#include <hip/hip_runtime.h>

#define B_ 2
#define S_ 4096
#define DIM_ 2048
#define H_ 16
#define HK_ 8
#define HD_ 128
#define M_ 128

typedef unsigned short u16;
typedef __bf16 bf16x8 __attribute__((ext_vector_type(8)));
typedef float f32x4 __attribute__((ext_vector_type(4)));

__device__ __forceinline__ u16 f2b(float f) {
  unsigned u = __float_as_uint(f);
  u = u + 0x7fffu + ((u >> 16) & 1u);
  return (u16)(u >> 16);
}
__device__ __forceinline__ float b2f(u16 h) {
  return __uint_as_float(((unsigned)h) << 16);
}
// monotone float<->uint encoding for atomicMax
__device__ __forceinline__ unsigned fenc(float f) {
  unsigned u = __float_as_uint(f);
  return (u & 0x80000000u) ? ~u : (u | 0x80000000u);
}
__device__ __forceinline__ float fdec(unsigned e) {
  unsigned u = (e & 0x80000000u) ? (e & 0x7fffffffu) : ~e;
  return __uint_as_float(u);
}

// ---------------- fp32 -> bf16 convert ----------------
__global__ void f2b_kernel(const float* __restrict__ in, u16* __restrict__ out, int n4) {
  int i = blockIdx.x * blockDim.x + threadIdx.x;
  if (i < n4) {
    float4 v = ((const float4*)in)[i];
    ushort4 o;
    o.x = f2b(v.x); o.y = f2b(v.y); o.z = f2b(v.z); o.w = f2b(v.w);
    ((ushort4*)out)[i] = o;
  }
}

// ---------------- proj transpose (128x128) ----------------
__global__ void tproj_kernel(const float* __restrict__ p, float* __restrict__ pT) {
  int i = blockIdx.x * 256 + threadIdx.x;  // 16384
  int d = i >> 7, m = i & 127;
  pT[i] = p[m * 128 + d];   // pT[d][m] = p[m][d]
}

// ---------------- zero-init scratch accumulators ----------------
__global__ void init_kernel(float* __restrict__ kvf, unsigned* __restrict__ kmaxu,
                            float* __restrict__ ksum) {
  int i = blockIdx.x * 256 + threadIdx.x;      // 262144 threads
  if (i < B_ * HK_ * M_ * HD_) kvf[i] = 0.f;
  if (i < B_ * HK_ * M_) { kmaxu[i] = 0u; ksum[i] = 0.f; }
}

// ---------------- m97-style bf16 B^T GEMM, batched + split-K ----------------
// C[M,N] = A[M,K] * B[N,K]^T ; 128x128 tile, BK=32, 4 waves, 16x16x32 MFMA
__global__ __launch_bounds__(256) void gemm_bt(
    const u16* __restrict__ A, const u16* __restrict__ Bm, float* __restrict__ C,
    int M, int N, int K,
    unsigned long long sAb, unsigned long long sBb, unsigned long long sCb,
    int bshiftB, int ldc, int ksplit)
{
  __shared__ __align__(16) u16 sA[128 * 32];
  __shared__ __align__(16) u16 sB[128 * 32];
  const int t = threadIdx.x;
  const int wave = t >> 6, lane = t & 63;
  const int z = blockIdx.z;
  const int batch = z / ksplit;
  const int ks = z - batch * ksplit;
  const int kLen = K / ksplit, kBeg = ks * kLen;

  const u16* Ab = A + (size_t)batch * sAb + (size_t)blockIdx.x * 128 * (size_t)K;
  const u16* Bb = Bm + (size_t)(batch >> bshiftB) * sBb + (size_t)blockIdx.y * 128 * (size_t)K;
  float* Cb = C + (size_t)batch * sCb + (size_t)blockIdx.x * 128 * (size_t)ldc
                + (size_t)blockIdx.y * 128;

  // staging geometry: tile is [128 rows][32 cols] bf16 = 8KB; chunk = issue*4+wave,
  // each chunk = 64 lanes * 16B = 1KB (wave-uniform LDS base, linear dest)
  const int r0 = wave * 16 + (lane >> 2);
  const int e0 = (lane & 3) * 8;
  const int wr = wave >> 1, wc = wave & 1;

  f32x4 acc[4][4] = {};

  for (int k0 = kBeg; k0 < kBeg + kLen; k0 += 32) {
#pragma unroll
    for (int i = 0; i < 2; i++) {
      __builtin_amdgcn_global_load_lds(
          (const __attribute__((address_space(1))) void*)(Ab + (size_t)(r0 + i * 64) * K + k0 + e0),
          (__attribute__((address_space(3))) void*)(&sA[(i * 4 + wave) * 512]), 16, 0, 0);
      __builtin_amdgcn_global_load_lds(
          (const __attribute__((address_space(1))) void*)(Bb + (size_t)(r0 + i * 64) * K + k0 + e0),
          (__attribute__((address_space(3))) void*)(&sB[(i * 4 + wave) * 512]), 16, 0, 0);
    }
    __syncthreads();   // drains vmcnt(0): staged data visible
    bf16x8 av[4], bv[4];
#pragma unroll
    for (int m = 0; m < 4; m++)
      av[m] = *(const bf16x8*)&sA[(wr * 64 + m * 16 + (lane & 15)) * 32 + (lane >> 4) * 8];
#pragma unroll
    for (int n = 0; n < 4; n++)
      bv[n] = *(const bf16x8*)&sB[(wc * 64 + n * 16 + (lane & 15)) * 32 + (lane >> 4) * 8];
#pragma unroll
    for (int m = 0; m < 4; m++)
#pragma unroll
      for (int n = 0; n < 4; n++)
        acc[m][n] = __builtin_amdgcn_mfma_f32_16x16x32_bf16(av[m], bv[n], acc[m][n], 0, 0, 0);
    __syncthreads();   // all reads done before next stage overwrites
  }

  const int crow0 = wr * 64 + (lane >> 4) * 4;
  const int ccol = wc * 64 + (lane & 15);
  if (ksplit == 1) {
#pragma unroll
    for (int m = 0; m < 4; m++)
#pragma unroll
      for (int n = 0; n < 4; n++)
#pragma unroll
        for (int r = 0; r < 4; r++)
          Cb[(size_t)(crow0 + m * 16 + r) * ldc + ccol + n * 16] = acc[m][n][r];
  } else {
#pragma unroll
    for (int m = 0; m < 4; m++)
#pragma unroll
      for (int n = 0; n < 4; n++)
#pragma unroll
        for (int r = 0; r < 4; r++)
          atomicAdd(&Cb[(size_t)(crow0 + m * 16 + r) * ldc + ccol + n * 16], acc[m][n][r]);
  }
}

// ---------------- RMSNorm + RoPE + FAVOR features (fp32) ----------------
// block = 4 waves, each wave = 4 tokens of one (b, head). lane holds rope pair i=lane.
template <int IS_Q>
__global__ __launch_bounds__(256) void favor_kernel(
    const float* __restrict__ qkv, const float* __restrict__ fc,
    const float* __restrict__ g, const float* __restrict__ pT,
    float* __restrict__ kpre, unsigned* __restrict__ kmaxu,
    u16* __restrict__ qphib, const float* __restrict__ ksum, float* __restrict__ denom,
    int colbase)
{
  const int b = blockIdx.z, h = blockIdx.y;
  const int wave = threadIdx.x >> 6, lane = threadIdx.x & 63;
  const int s0 = blockIdx.x * 16 + wave * 4;
  __shared__ float xs[4][4][128];
  float halfss[4];
  const int col = colbase + h * HD_;

#pragma unroll
  for (int tt = 0; tt < 4; tt++) {
    const int s = s0 + tt;
    const size_t row = (size_t)b * S_ + s;
    const float* xr = qkv + row * 4096 + col;
    float a = xr[2 * lane], bb = xr[2 * lane + 1];
    float ss = a * a + bb * bb;
#pragma unroll
    for (int o = 1; o < 64; o <<= 1) ss += __shfl_xor(ss, o);
    const float sc = rsqrtf(ss * (1.f / HD_) + 1e-5f);
    a *= sc * g[2 * lane];
    bb *= sc * g[2 * lane + 1];
    const float2 cs = *(const float2*)&fc[(row * 64 + lane) * 2];
    float na = a * cs.x - bb * cs.y;
    float nb = a * cs.y + bb * cs.x;
    na *= 0.29730177875068026f;   // 128^-0.25
    nb *= 0.29730177875068026f;
    xs[wave][tt][2 * lane] = na;
    xs[wave][tt][2 * lane + 1] = nb;
    float s2 = na * na + nb * nb;
#pragma unroll
    for (int o = 1; o < 64; o <<= 1) s2 += __shfl_xor(s2, o);
    halfss[tt] = 0.5f * s2;
  }

  float acc[4][2] = {};
  for (int d = 0; d < 128; d++) {
    const float2 p = *(const float2*)&pT[d * 128 + 2 * lane];
#pragma unroll
    for (int tt = 0; tt < 4; tt++) {
      const float xv = xs[wave][tt][d];   // LDS broadcast
      acc[tt][0] = fmaf(p.x, xv, acc[tt][0]);
      acc[tt][1] = fmaf(p.y, xv, acc[tt][1]);
    }
  }

  if (IS_Q) {
#pragma unroll
    for (int tt = 0; tt < 4; tt++) {
      const int s = s0 + tt;
      const float p0 = acc[tt][0] - halfss[tt], p1 = acc[tt][1] - halfss[tt];
      float mx = fmaxf(p0, p1);
#pragma unroll
      for (int o = 1; o < 64; o <<= 1) mx = fmaxf(mx, __shfl_xor(mx, o));
      const float f0 = expf(p0 - mx) * 0.08838834764831845f + 1e-6f;  // M^-0.5
      const float f1 = expf(p1 - mx) * 0.08838834764831845f + 1e-6f;
      const u16 u0 = f2b(f0), u1 = f2b(f1);
      const size_t base = (((size_t)(b * H_ + h)) * S_ + s) * M_;
      ushort2 st2; st2.x = u0; st2.y = u1;
      *(ushort2*)&qphib[base + 2 * lane] = st2;
      const float* ksb = ksum + ((b * HK_) + (h >> 1)) * M_;
      // denom with bf16-rounded phi for exact consistency with the MFMA numerator
      float dsum = b2f(u0) * ksb[2 * lane] + b2f(u1) * ksb[2 * lane + 1];
#pragma unroll
      for (int o = 1; o < 64; o <<= 1) dsum += __shfl_xor(dsum, o);
      if (lane == 0) denom[((size_t)(b * H_ + h)) * S_ + s] = dsum;
    }
  } else {
    float mx0 = -1e30f, mx1 = -1e30f;
#pragma unroll
    for (int tt = 0; tt < 4; tt++) {
      const int s = s0 + tt;
      const float p0 = acc[tt][0] - halfss[tt], p1 = acc[tt][1] - halfss[tt];
      const size_t base = (((size_t)(b * HK_ + h)) * S_ + s) * M_;
      float2 w2; w2.x = p0; w2.y = p1;
      *(float2*)&kpre[base + 2 * lane] = w2;
      mx0 = fmaxf(mx0, p0);
      mx1 = fmaxf(mx1, p1);
    }
    unsigned* km = kmaxu + (b * HK_ + h) * M_;
    atomicMax(&km[2 * lane], fenc(mx0));
    atomicMax(&km[2 * lane + 1], fenc(mx1));
  }
}

// ---------------- k-side: exp(pre - max), mask, transpose to [m][s], k_sum ----------------
__global__ __launch_bounds__(256) void kexp_kernel(
    const float* __restrict__ kpre, const unsigned* __restrict__ kmaxu,
    const int* __restrict__ amask, u16* __restrict__ kphiT, float* __restrict__ ksum)
{
  const int b = blockIdx.z, hk = blockIdx.y;
  const int c0 = blockIdx.x * 64;
  const int t = threadIdx.x;
  const int m = t & 127, half = t >> 7;
  __shared__ __align__(16) u16 st[128][64];
  __shared__ float red[256];
  const int bhk = b * HK_ + hk;
  const float kmax = fdec(kmaxu[bhk * M_ + m]);
  float sum = 0.f;
  for (int i = 0; i < 32; i++) {
    const int sl = half * 32 + i;
    const int s = c0 + sl;
    const float pre = kpre[(((size_t)bhk) * S_ + s) * M_ + m];
    const int va = amask[b * S_ + s] > 0;
    const float phi = va ? (expf(pre - kmax) * 0.08838834764831845f + 1e-6f) : 0.f;
    sum += phi;
    st[m][sl] = f2b(phi);
  }
  red[t] = sum;
  __syncthreads();
  if (t < 128) atomicAdd(&ksum[bhk * M_ + t], red[t] + red[t + 128]);
  const int mr = t >> 1, part = t & 1;
  const size_t base = ((size_t)(bhk * M_ + mr)) * S_ + c0 + part * 32;
#pragma unroll
  for (int k = 0; k < 4; k++)
    *(uint4*)&kphiT[base + k * 8] = *(const uint4*)&st[mr][part * 32 + k * 8];
}

// ---------------- v: mask + bf16 + transpose to [d][s] ----------------
__global__ __launch_bounds__(256) void vT_kernel(
    const float* __restrict__ qkv, const int* __restrict__ amask, u16* __restrict__ vT)
{
  const int b = blockIdx.z, hk = blockIdx.y;
  const int c0 = blockIdx.x * 64;
  const int t = threadIdx.x;
  const int d = t & 127, half = t >> 7;
  __shared__ __align__(16) u16 st[128][64];
  const int bhk = b * HK_ + hk;
  for (int i = 0; i < 32; i++) {
    const int sl = half * 32 + i;
    const int s = c0 + sl;
    const float v = qkv[((size_t)(b * S_ + s)) * 4096 + 3072 + hk * 128 + d];
    const int va = amask[b * S_ + s] > 0;
    st[d][sl] = f2b(va ? v : 0.f);
  }
  __syncthreads();
  const int dr = t >> 1, part = t & 1;
  const size_t base = ((size_t)(bhk * 128 + dr)) * S_ + c0 + part * 32;
#pragma unroll
  for (int k = 0; k < 4; k++)
    *(uint4*)&vT[base + k * 8] = *(const uint4*)&st[dr][part * 32 + k * 8];
}

// ---------------- kv fp32 -> bf16, transpose [m][d] -> [d][m] ----------------
__global__ void kvb_kernel(const float* __restrict__ kvf, u16* __restrict__ kvb) {
  const int i = blockIdx.x * 256 + threadIdx.x;  // 262144 = 16*128*128
  const int bhk = i >> 14;
  const int rem = i & 16383;
  const int d = rem >> 7, m = rem & 127;
  kvb[i] = f2b(kvf[(bhk << 14) + m * 128 + d]);
}

// ---------------- epilogue: divide by denom, mask, transpose heads, bf16 ----------------
__global__ __launch_bounds__(256) void epi_kernel(
    const float* __restrict__ oraw, const float* __restrict__ denom,
    const int* __restrict__ amask, u16* __restrict__ attnb)
{
  const int tid = blockIdx.x * 256 + threadIdx.x;  // 4,194,304 threads, 4 elems each
  const int d4 = tid & 31;
  const int s = (tid >> 5) & (S_ - 1);
  const int h = (tid >> 17) & (H_ - 1);
  const int b = tid >> 21;
  const float den = denom[((size_t)(b * H_ + h)) * S_ + s] + 1e-6f;
  const float vm = (amask[b * S_ + s] > 0) ? 1.f : 0.f;
  const float4 v = *(const float4*)&oraw[(((size_t)(b * H_ + h)) * S_ + s) * HD_ + d4 * 4];
  const float inv = vm / den;
  ushort4 o;
  o.x = f2b(v.x * inv); o.y = f2b(v.y * inv); o.z = f2b(v.z * inv); o.w = f2b(v.w * inv);
  *(ushort4*)&attnb[((size_t)(b * S_ + s)) * 2048 + h * 128 + d4 * 4] = o;
}

extern "C" void kernel_launch(void* const* d_in, const int* in_sizes, int n_in,
                              void* d_out, int out_size, void* d_ws, size_t ws_size,
                              hipStream_t stream)
{
  const float* x  = (const float*)d_in[0];
  const int*   am = (const int*)d_in[1];
  const float* fc = (const float*)d_in[2];
  const float* wq = (const float*)d_in[3];
  const float* wk = (const float*)d_in[4];
  const float* wv = (const float*)d_in[5];
  const float* wo = (const float*)d_in[6];
  const float* gq = (const float*)d_in[7];
  const float* gk = (const float*)d_in[8];
  const float* pj = (const float*)d_in[9];
  float* out = (float*)d_out;

  // workspace layout (bytes), with dead-buffer aliasing:
  //   attnb aliases xb   (xb dead after QKV GEMM; attnb written by epi, much later)
  //   qphib aliases kpre (kpre dead after kexp; qphib written by favor<1>, later)
  char* w = (char*)d_ws;
  size_t off = 0;
  u16*   xb    = (u16*)(w + off);  off += (size_t)B_ * S_ * DIM_ * 2;          // 33,554,432
  u16*   wqkvb = (u16*)(w + off);  off += 4096ull * 2048 * 2;                  // 16,777,216
  u16*   wob   = (u16*)(w + off);  off += 2048ull * 2048 * 2;                  // 8,388,608
  float* qkv   = (float*)(w + off); off += (size_t)B_ * S_ * 4096 * 4;        // 134,217,728 (later aliased as oraw)
  float* kpre  = (float*)(w + off); off += (size_t)B_ * HK_ * S_ * M_ * 4;    // 33,554,432 (later aliased as qphib)
  u16*   kphiT = (u16*)(w + off);  off += (size_t)B_ * HK_ * S_ * M_ * 2;      // 16,777,216
  u16*   vT    = (u16*)(w + off);  off += (size_t)B_ * HK_ * S_ * HD_ * 2;     // 16,777,216
  float* kvf   = (float*)(w + off); off += (size_t)B_ * HK_ * M_ * HD_ * 4;   // 1,048,576
  u16*   kvb   = (u16*)(w + off);  off += (size_t)B_ * HK_ * M_ * HD_ * 2;     // 524,288
  float* pT    = (float*)(w + off); off += 128ull * 128 * 4;                  // 65,536
  unsigned* kmaxu = (unsigned*)(w + off); off += (size_t)B_ * HK_ * M_ * 4;   // 8,192
  float* ksum  = (float*)(w + off); off += (size_t)B_ * HK_ * M_ * 4;         // 8,192
  float* denom = (float*)(w + off); off += (size_t)B_ * H_ * S_ * 4;          // 524,288
  u16*   attnb = xb;                 // alias
  u16*   qphib = (u16*)kpre;         // alias
  if (ws_size < off) return;  // ~263 MB required

  // converts + init
  f2b_kernel<<<16384, 256, 0, stream>>>(x, xb, 4194304);
  f2b_kernel<<<4096, 256, 0, stream>>>(wq, wqkvb, 1048576);
  f2b_kernel<<<2048, 256, 0, stream>>>(wk, wqkvb + 4194304, 524288);
  f2b_kernel<<<2048, 256, 0, stream>>>(wv, wqkvb + 6291456, 524288);
  f2b_kernel<<<4096, 256, 0, stream>>>(wo, wob, 1048576);
  tproj_kernel<<<64, 256, 0, stream>>>(pj, pT);
  init_kernel<<<1024, 256, 0, stream>>>(kvf, kmaxu, ksum);

  // QKV projection: [8192,4096] = xb[8192,2048] @ wqkvb[4096,2048]^T
  gemm_bt<<<dim3(64, 32, 1), 256, 0, stream>>>(xb, wqkvb, qkv,
      8192, 4096, 2048, 0ull, 0ull, 0ull, 0, 4096, 1);

  // k-side features (pre-exp) + running max over s
  favor_kernel<0><<<dim3(S_ / 16, HK_, B_), 256, 0, stream>>>(
      qkv, fc, gk, pT, kpre, kmaxu, nullptr, nullptr, nullptr, 2048);
  // exp + mask + transpose + k_sum
  kexp_kernel<<<dim3(S_ / 64, HK_, B_), 256, 0, stream>>>(kpre, kmaxu, am, kphiT, ksum);
  vT_kernel<<<dim3(S_ / 64, HK_, B_), 256, 0, stream>>>(qkv, am, vT);
  // q-side features + denom (needs ksum); writes qphib (aliases dead kpre)
  favor_kernel<1><<<dim3(S_ / 16, H_, B_), 256, 0, stream>>>(
      qkv, fc, gq, pT, nullptr, nullptr, qphib, ksum, denom, 0);

  // kv[m,d] = sum_s kphi[s,m] v[s,d] : 16 batches, K=4096, split-K 16, atomicAdd
  gemm_bt<<<dim3(1, 1, 256), 256, 0, stream>>>(kphiT, vT, kvf,
      128, 128, 4096, 524288ull, 524288ull, 16384ull, 0, 128, 16);
  kvb_kernel<<<1024, 256, 0, stream>>>(kvf, kvb);

  // out[s,d] = qphi[s,m] @ kv[m,d] : 32 batches (b,h), kv batch = (b*16+h)>>1 = b*8+h/2
  gemm_bt<<<dim3(32, 1, 32), 256, 0, stream>>>(qphib, kvb, qkv /*oraw*/,
      4096, 128, 128, 524288ull, 16384ull, 524288ull, 1, 128, 1);

  // divide by denom, mask, head-transpose, bf16 (attnb aliases dead xb)
  epi_kernel<<<16384, 256, 0, stream>>>(qkv, denom, am, attnb);

  // final projection: [8192,2048] = attnb @ wob^T
  gemm_bt<<<dim3(64, 16, 1), 256, 0, stream>>>(attnb, wob, out,
      8192, 2048, 2048, 0ull, 0ull, 0ull, 0, 2048, 1);
}

// Round 3
// 694.401 us; speedup vs baseline: 1.2033x; 1.2033x over previous
//
#include <hip/hip_runtime.h>

#define B_ 2
#define S_ 4096
#define DIM_ 2048
#define H_ 16
#define HK_ 8
#define HD_ 128
#define M_ 128

typedef unsigned short u16;
typedef __bf16 bf16x8 __attribute__((ext_vector_type(8)));
typedef float f32x4 __attribute__((ext_vector_type(4)));

__device__ __forceinline__ u16 f2b(float f) {
  unsigned u = __float_as_uint(f);
  u = u + 0x7fffu + ((u >> 16) & 1u);
  return (u16)(u >> 16);
}
__device__ __forceinline__ float b2f(u16 h) {
  return __uint_as_float(((unsigned)h) << 16);
}
__device__ __forceinline__ unsigned fenc(float f) {
  unsigned u = __float_as_uint(f);
  return (u & 0x80000000u) ? ~u : (u | 0x80000000u);
}
__device__ __forceinline__ float fdec(unsigned e) {
  unsigned u = (e & 0x80000000u) ? (e & 0x7fffffffu) : ~e;
  return __uint_as_float(u);
}

// ---------------- fp32 -> bf16 convert ----------------
__global__ void f2b_kernel(const float* __restrict__ in, u16* __restrict__ out, int n4) {
  int i = blockIdx.x * blockDim.x + threadIdx.x;
  if (i < n4) {
    float4 v = ((const float4*)in)[i];
    ushort4 o;
    o.x = f2b(v.x); o.y = f2b(v.y); o.z = f2b(v.z); o.w = f2b(v.w);
    ((ushort4*)out)[i] = o;
  }
}

// ---------------- proj transpose (128x128) ----------------
__global__ void tproj_kernel(const float* __restrict__ p, float* __restrict__ pT) {
  int i = blockIdx.x * 256 + threadIdx.x;  // 16384
  int d = i >> 7, m = i & 127;
  pT[i] = p[m * 128 + d];   // pT[d][m] = p[m][d]
}

// ---------------- zero-init scratch accumulators ----------------
__global__ void init_kernel(float* __restrict__ kvf, unsigned* __restrict__ kmaxu,
                            float* __restrict__ ksum) {
  int i = blockIdx.x * 256 + threadIdx.x;      // 262144 threads
  if (i < B_ * HK_ * M_ * HD_) kvf[i] = 0.f;
  if (i < B_ * HK_ * M_) { kmaxu[i] = 0u; ksum[i] = 0.f; }
}

// ================= 256x256 8-phase bf16 GEMM (T2+T3+T4+T5) =================
// C[M,N] = A[M,K] * B[N,K]^T, fp32 out. 512 thr (8 waves 2Mx4N), BK=64,
// LDS 128KiB (2 dbuf x [A|B] x 2 halves x 128x64 bf16), XOR-swizzle (row&7)<<4.
// Deep prefetch: whole next K-tile staged at phase 0; single vmcnt(0)/tile.
__global__ __launch_bounds__(512, 2) void gemm256(
    const u16* __restrict__ A, const u16* __restrict__ Bm, float* __restrict__ C,
    int K, int ldc, int nbx)
{
  __shared__ __align__(16) u16 lds[65536];   // 128 KiB
  const int t = threadIdx.x;
  const int wave = t >> 6, lane = t & 63;
  const int nwg = gridDim.x;
  const int q8 = nwg >> 3;
  const int id = blockIdx.x;
  const int sid = (id & 7) * q8 + (id >> 3);      // XCD swizzle (nwg % 8 == 0)
  const int nby = nwg / nbx;
  const int by = sid % nby;
  const int bx = sid / nby;
  const int wave_m = wave >> 2;      // 0..1
  const int wave_n = wave & 3;       // 0..3
  const int lr = lane & 15, lg = lane >> 4;

  // staging constants: linear LDS dest, pre-swizzled global source (rule 21)
  const int srow = lane >> 3;                       // row&7 within 8-row stripe
  const int scolE = (((lane & 7) ^ srow) << 3);     // source col in elements

  const int NT = K >> 6;
  f32x4 acc[8][4] = {};

  const u16* Abase = A + (size_t)bx * 256 * (size_t)K;
  const u16* Bbase = Bm + (size_t)by * 256 * (size_t)K;

#define STAGE256(buf, k0)                                                            \
  {                                                                                  \
    _Pragma("unroll")                                                                \
    for (int sub = 0; sub < 2; sub++) {                                              \
      const int rowH = (wave * 2 + sub) * 8 + srow;                                  \
      const int chunk = (wave * 2 + sub) * 512;                                      \
      _Pragma("unroll")                                                              \
      for (int hh = 0; hh < 2; hh++) {                                               \
        __builtin_amdgcn_global_load_lds(                                            \
            (const __attribute__((address_space(1))) void*)(Abase + (size_t)(hh * 128 + rowH) * K + (k0) + scolE), \
            (__attribute__((address_space(3))) void*)&lds[(buf) * 16384 + hh * 8192 + chunk], 16, 0, 0); \
        __builtin_amdgcn_global_load_lds(                                            \
            (const __attribute__((address_space(1))) void*)(Bbase + (size_t)(hh * 128 + rowH) * K + (k0) + scolE), \
            (__attribute__((address_space(3))) void*)&lds[32768 + (buf) * 16384 + hh * 8192 + chunk], 16, 0, 0); \
      }                                                                              \
    }                                                                                \
  }

  STAGE256(0, 0);
  __syncthreads();   // prologue drain (vmcnt 0 + barrier)

  for (int tt = 0; tt < NT; tt++) {
    const int cur = tt & 1;
    const int AbaseH = cur * 16384 + wave_m * 8192;
    const int BbaseH = 32768 + cur * 16384 + (wave_n >> 1) * 8192;
#pragma unroll
    for (int q = 0; q < 4; q++) {
      if (q == 0 && tt + 1 < NT) { STAGE256(cur ^ 1, (tt + 1) * 64) }
      const int mh = q >> 1, nh = q & 1;
      bf16x8 af[4][2], bfr[2][2];
#pragma unroll
      for (int m = 0; m < 4; m++) {
        const int r = mh * 64 + m * 16 + lr;
#pragma unroll
        for (int kk = 0; kk < 2; kk++) {
          const int cb = ((kk << 6) | (lg << 4)) ^ ((lr & 7) << 4);
          af[m][kk] = *(const bf16x8*)&lds[AbaseH + r * 64 + (cb >> 1)];
        }
      }
#pragma unroll
      for (int n = 0; n < 2; n++) {
        const int r = (wave_n & 1) * 64 + nh * 32 + n * 16 + lr;
#pragma unroll
        for (int kk = 0; kk < 2; kk++) {
          const int cb = ((kk << 6) | (lg << 4)) ^ ((lr & 7) << 4);
          bfr[n][kk] = *(const bf16x8*)&lds[BbaseH + r * 64 + (cb >> 1)];
        }
      }
      asm volatile("" ::: "memory");
      __builtin_amdgcn_s_barrier();
      asm volatile("" ::: "memory");
      __builtin_amdgcn_s_setprio(1);
#pragma unroll
      for (int kk = 0; kk < 2; kk++)
#pragma unroll
        for (int m = 0; m < 4; m++)
#pragma unroll
          for (int n = 0; n < 2; n++)
            acc[mh * 4 + m][nh * 2 + n] =
                __builtin_amdgcn_mfma_f32_16x16x32_bf16(af[m][kk], bfr[n][kk],
                                                        acc[mh * 4 + m][nh * 2 + n], 0, 0, 0);
      __builtin_amdgcn_s_setprio(0);
      asm volatile("" ::: "memory");
      if (q == 3) asm volatile("s_waitcnt vmcnt(0)" ::: "memory");  // tile boundary: loads are ~4 phases old
      __builtin_amdgcn_s_barrier();
      asm volatile("" ::: "memory");
    }
  }

  float* Cb = C + (size_t)(bx * 256 + wave_m * 128 + lg * 4) * ldc + by * 256 + wave_n * 64 + lr;
#pragma unroll
  for (int i = 0; i < 8; i++)
#pragma unroll
    for (int j = 0; j < 4; j++)
#pragma unroll
      for (int r = 0; r < 4; r++)
        Cb[(size_t)(i * 16 + r) * ldc + j * 16] = acc[i][j][r];
#undef STAGE256
}

// ---------------- m97-style bf16 B^T GEMM (kept for the small kv GEMM) ----------------
__global__ __launch_bounds__(256) void gemm_bt(
    const u16* __restrict__ A, const u16* __restrict__ Bm, float* __restrict__ C,
    int M, int N, int K,
    unsigned long long sAb, unsigned long long sBb, unsigned long long sCb,
    int bshiftB, int ldc, int ksplit)
{
  __shared__ __align__(16) u16 sA[128 * 32];
  __shared__ __align__(16) u16 sB[128 * 32];
  const int t = threadIdx.x;
  const int wave = t >> 6, lane = t & 63;
  const int z = blockIdx.z;
  const int batch = z / ksplit;
  const int ks = z - batch * ksplit;
  const int kLen = K / ksplit, kBeg = ks * kLen;

  const u16* Ab = A + (size_t)batch * sAb + (size_t)blockIdx.x * 128 * (size_t)K;
  const u16* Bb = Bm + (size_t)(batch >> bshiftB) * sBb + (size_t)blockIdx.y * 128 * (size_t)K;
  float* Cb = C + (size_t)batch * sCb + (size_t)blockIdx.x * 128 * (size_t)ldc
                + (size_t)blockIdx.y * 128;

  const int r0 = wave * 16 + (lane >> 2);
  const int e0 = (lane & 3) * 8;
  const int wr = wave >> 1, wc = wave & 1;

  f32x4 acc[4][4] = {};

  for (int k0 = kBeg; k0 < kBeg + kLen; k0 += 32) {
#pragma unroll
    for (int i = 0; i < 2; i++) {
      __builtin_amdgcn_global_load_lds(
          (const __attribute__((address_space(1))) void*)(Ab + (size_t)(r0 + i * 64) * K + k0 + e0),
          (__attribute__((address_space(3))) void*)(&sA[(i * 4 + wave) * 512]), 16, 0, 0);
      __builtin_amdgcn_global_load_lds(
          (const __attribute__((address_space(1))) void*)(Bb + (size_t)(r0 + i * 64) * K + k0 + e0),
          (__attribute__((address_space(3))) void*)(&sB[(i * 4 + wave) * 512]), 16, 0, 0);
    }
    __syncthreads();
    bf16x8 av[4], bv[4];
#pragma unroll
    for (int m = 0; m < 4; m++)
      av[m] = *(const bf16x8*)&sA[(wr * 64 + m * 16 + (lane & 15)) * 32 + (lane >> 4) * 8];
#pragma unroll
    for (int n = 0; n < 4; n++)
      bv[n] = *(const bf16x8*)&sB[(wc * 64 + n * 16 + (lane & 15)) * 32 + (lane >> 4) * 8];
#pragma unroll
    for (int m = 0; m < 4; m++)
#pragma unroll
      for (int n = 0; n < 4; n++)
        acc[m][n] = __builtin_amdgcn_mfma_f32_16x16x32_bf16(av[m], bv[n], acc[m][n], 0, 0, 0);
    __syncthreads();
  }

  const int crow0 = wr * 64 + (lane >> 4) * 4;
  const int ccol = wc * 64 + (lane & 15);
  if (ksplit == 1) {
#pragma unroll
    for (int m = 0; m < 4; m++)
#pragma unroll
      for (int n = 0; n < 4; n++)
#pragma unroll
        for (int r = 0; r < 4; r++)
          Cb[(size_t)(crow0 + m * 16 + r) * ldc + ccol + n * 16] = acc[m][n][r];
  } else {
#pragma unroll
    for (int m = 0; m < 4; m++)
#pragma unroll
      for (int n = 0; n < 4; n++)
#pragma unroll
        for (int r = 0; r < 4; r++)
          atomicAdd(&Cb[(size_t)(crow0 + m * 16 + r) * ldc + ccol + n * 16], acc[m][n][r]);
  }
}

// ---------------- out = qphi @ kv^T with fused denom/mask/bf16/head-transpose ----------------
__global__ __launch_bounds__(256) void gemm_out_epi(
    const u16* __restrict__ qphib, const u16* __restrict__ kvb,
    const float* __restrict__ denom, const int* __restrict__ amask,
    u16* __restrict__ attnb)
{
  __shared__ __align__(16) u16 sA[128 * 32];
  __shared__ __align__(16) u16 sB[128 * 32];
  const int t = threadIdx.x;
  const int wave = t >> 6, lane = t & 63;
  const int batch = blockIdx.z;           // b*16 + h
  const int b = batch >> 4, h = batch & 15;

  const u16* Ab = qphib + (size_t)batch * 524288 + (size_t)blockIdx.x * 128 * 128;
  const u16* Bb = kvb + (size_t)(batch >> 1) * 16384;

  const int r0 = wave * 16 + (lane >> 2);
  const int e0 = (lane & 3) * 8;
  const int wr = wave >> 1, wc = wave & 1;

  f32x4 acc[4][4] = {};

  for (int k0 = 0; k0 < 128; k0 += 32) {
#pragma unroll
    for (int i = 0; i < 2; i++) {
      __builtin_amdgcn_global_load_lds(
          (const __attribute__((address_space(1))) void*)(Ab + (size_t)(r0 + i * 64) * 128 + k0 + e0),
          (__attribute__((address_space(3))) void*)(&sA[(i * 4 + wave) * 512]), 16, 0, 0);
      __builtin_amdgcn_global_load_lds(
          (const __attribute__((address_space(1))) void*)(Bb + (size_t)(r0 + i * 64) * 128 + k0 + e0),
          (__attribute__((address_space(3))) void*)(&sB[(i * 4 + wave) * 512]), 16, 0, 0);
    }
    __syncthreads();
    bf16x8 av[4], bv[4];
#pragma unroll
    for (int m = 0; m < 4; m++)
      av[m] = *(const bf16x8*)&sA[(wr * 64 + m * 16 + (lane & 15)) * 32 + (lane >> 4) * 8];
#pragma unroll
    for (int n = 0; n < 4; n++)
      bv[n] = *(const bf16x8*)&sB[(wc * 64 + n * 16 + (lane & 15)) * 32 + (lane >> 4) * 8];
#pragma unroll
    for (int m = 0; m < 4; m++)
#pragma unroll
      for (int n = 0; n < 4; n++)
        acc[m][n] = __builtin_amdgcn_mfma_f32_16x16x32_bf16(av[m], bv[n], acc[m][n], 0, 0, 0);
    __syncthreads();
  }

  const int crow0 = wr * 64 + (lane >> 4) * 4;
  const int ccol = wc * 64 + (lane & 15);
#pragma unroll
  for (int m = 0; m < 4; m++)
#pragma unroll
    for (int r = 0; r < 4; r++) {
      const int s = blockIdx.x * 128 + crow0 + m * 16 + r;
      const float inv = (amask[b * S_ + s] > 0)
                          ? 1.f / (denom[(size_t)batch * S_ + s] + 1e-6f) : 0.f;
      u16* orow = attnb + ((size_t)(b * S_ + s)) * 2048 + h * 128 + ccol;
#pragma unroll
      for (int n = 0; n < 4; n++)
        orow[n * 16] = f2b(acc[m][n][r] * inv);
    }
}

// ---------------- RMSNorm + RoPE + FAVOR features (fp32) ----------------
template <int IS_Q>
__global__ __launch_bounds__(256) void favor_kernel(
    const float* __restrict__ qkv, const float* __restrict__ fc,
    const float* __restrict__ g, const float* __restrict__ pT,
    float* __restrict__ kpre, unsigned* __restrict__ kmaxu,
    u16* __restrict__ qphib, const float* __restrict__ ksum, float* __restrict__ denom,
    int colbase)
{
  const int b = blockIdx.z, h = blockIdx.y;
  const int wave = threadIdx.x >> 6, lane = threadIdx.x & 63;
  const int s0 = blockIdx.x * 16 + wave * 4;
  __shared__ float xs[4][4][128];
  __shared__ float sm[4][128];
  float halfss[4];
  const int col = colbase + h * HD_;

#pragma unroll
  for (int tt = 0; tt < 4; tt++) {
    const int s = s0 + tt;
    const size_t row = (size_t)b * S_ + s;
    const float* xr = qkv + row * 4096 + col;
    float a = xr[2 * lane], bb = xr[2 * lane + 1];
    float ss = a * a + bb * bb;
#pragma unroll
    for (int o = 1; o < 64; o <<= 1) ss += __shfl_xor(ss, o);
    const float sc = rsqrtf(ss * (1.f / HD_) + 1e-5f);
    a *= sc * g[2 * lane];
    bb *= sc * g[2 * lane + 1];
    const float2 cs = *(const float2*)&fc[(row * 64 + lane) * 2];
    float na = a * cs.x - bb * cs.y;
    float nb = a * cs.y + bb * cs.x;
    na *= 0.29730177875068026f;   // 128^-0.25
    nb *= 0.29730177875068026f;
    xs[wave][tt][2 * lane] = na;
    xs[wave][tt][2 * lane + 1] = nb;
    float s2 = na * na + nb * nb;
#pragma unroll
    for (int o = 1; o < 64; o <<= 1) s2 += __shfl_xor(s2, o);
    halfss[tt] = 0.5f * s2;
  }

  float acc[4][2] = {};
  for (int d = 0; d < 128; d++) {
    const float2 p = *(const float2*)&pT[d * 128 + 2 * lane];
#pragma unroll
    for (int tt = 0; tt < 4; tt++) {
      const float xv = xs[wave][tt][d];
      acc[tt][0] = fmaf(p.x, xv, acc[tt][0]);
      acc[tt][1] = fmaf(p.y, xv, acc[tt][1]);
    }
  }

  if (IS_Q) {
#pragma unroll
    for (int tt = 0; tt < 4; tt++) {
      const int s = s0 + tt;
      const float p0 = acc[tt][0] - halfss[tt], p1 = acc[tt][1] - halfss[tt];
      float mx = fmaxf(p0, p1);
#pragma unroll
      for (int o = 1; o < 64; o <<= 1) mx = fmaxf(mx, __shfl_xor(mx, o));
      const float f0 = expf(p0 - mx) * 0.08838834764831845f + 1e-6f;  // M^-0.5
      const float f1 = expf(p1 - mx) * 0.08838834764831845f + 1e-6f;
      const u16 u0 = f2b(f0), u1 = f2b(f1);
      const size_t base = (((size_t)(b * H_ + h)) * S_ + s) * M_;
      ushort2 st2; st2.x = u0; st2.y = u1;
      *(ushort2*)&qphib[base + 2 * lane] = st2;
      const float* ksb = ksum + ((b * HK_) + (h >> 1)) * M_;
      float dsum = b2f(u0) * ksb[2 * lane] + b2f(u1) * ksb[2 * lane + 1];
#pragma unroll
      for (int o = 1; o < 64; o <<= 1) dsum += __shfl_xor(dsum, o);
      if (lane == 0) denom[((size_t)(b * H_ + h)) * S_ + s] = dsum;
    }
  } else {
    float mx0 = -1e30f, mx1 = -1e30f;
#pragma unroll
    for (int tt = 0; tt < 4; tt++) {
      const int s = s0 + tt;
      const float p0 = acc[tt][0] - halfss[tt], p1 = acc[tt][1] - halfss[tt];
      const size_t base = (((size_t)(b * HK_ + h)) * S_ + s) * M_;
      float2 w2; w2.x = p0; w2.y = p1;
      *(float2*)&kpre[base + 2 * lane] = w2;
      mx0 = fmaxf(mx0, p0);
      mx1 = fmaxf(mx1, p1);
    }
    // block-level max reduce, then 1 atomic per (block, m): 4x fewer atomics
    sm[wave][2 * lane] = mx0;
    sm[wave][2 * lane + 1] = mx1;
    __syncthreads();
    if (threadIdx.x < 128) {
      const float v = fmaxf(fmaxf(sm[0][threadIdx.x], sm[1][threadIdx.x]),
                            fmaxf(sm[2][threadIdx.x], sm[3][threadIdx.x]));
      atomicMax(&kmaxu[(b * HK_ + h) * M_ + threadIdx.x], fenc(v));
    }
  }
}

// ---------------- k-side: exp(pre - max), mask, transpose to [m][s], k_sum ----------------
__global__ __launch_bounds__(256) void kexp_kernel(
    const float* __restrict__ kpre, const unsigned* __restrict__ kmaxu,
    const int* __restrict__ amask, u16* __restrict__ kphiT, float* __restrict__ ksum)
{
  const int b = blockIdx.z, hk = blockIdx.y;
  const int c0 = blockIdx.x * 64;
  const int t = threadIdx.x;
  const int m = t & 127, half = t >> 7;
  __shared__ __align__(16) u16 st[128][64];
  __shared__ float red[256];
  const int bhk = b * HK_ + hk;
  const float kmax = fdec(kmaxu[bhk * M_ + m]);
  float sum = 0.f;
  const int msw = (m & 7) << 3;     // XOR swizzle: 32-way -> ~4-way bank conflicts
  for (int i = 0; i < 32; i++) {
    const int sl = half * 32 + i;
    const int s = c0 + sl;
    const float pre = kpre[(((size_t)bhk) * S_ + s) * M_ + m];
    const int va = amask[b * S_ + s] > 0;
    const float phi = va ? (expf(pre - kmax) * 0.08838834764831845f + 1e-6f) : 0.f;
    sum += phi;
    st[m][sl ^ msw] = f2b(phi);
  }
  red[t] = sum;
  __syncthreads();
  if (t < 128) atomicAdd(&ksum[bhk * M_ + t], red[t] + red[t + 128]);
  const int mr = t >> 1, part = t & 1;
  const int rsw = (mr & 7) << 3;
  const size_t base = ((size_t)(bhk * M_ + mr)) * S_ + c0 + part * 32;
#pragma unroll
  for (int k = 0; k < 4; k++)
    *(uint4*)&kphiT[base + k * 8] = *(const uint4*)&st[mr][(part * 32 + k * 8) ^ rsw];
}

// ---------------- v: mask + bf16 + transpose to [d][s] ----------------
__global__ __launch_bounds__(256) void vT_kernel(
    const float* __restrict__ qkv, const int* __restrict__ amask, u16* __restrict__ vT)
{
  const int b = blockIdx.z, hk = blockIdx.y;
  const int c0 = blockIdx.x * 64;
  const int t = threadIdx.x;
  const int d = t & 127, half = t >> 7;
  __shared__ __align__(16) u16 st[128][64];
  const int bhk = b * HK_ + hk;
  const int dsw = (d & 7) << 3;
  for (int i = 0; i < 32; i++) {
    const int sl = half * 32 + i;
    const int s = c0 + sl;
    const float v = qkv[((size_t)(b * S_ + s)) * 4096 + 3072 + hk * 128 + d];
    const int va = amask[b * S_ + s] > 0;
    st[d][sl ^ dsw] = f2b(va ? v : 0.f);
  }
  __syncthreads();
  const int dr = t >> 1, part = t & 1;
  const int rsw = (dr & 7) << 3;
  const size_t base = ((size_t)(bhk * 128 + dr)) * S_ + c0 + part * 32;
#pragma unroll
  for (int k = 0; k < 4; k++)
    *(uint4*)&vT[base + k * 8] = *(const uint4*)&st[dr][(part * 32 + k * 8) ^ rsw];
}

// ---------------- kv fp32 -> bf16, transpose [m][d] -> [d][m] ----------------
__global__ void kvb_kernel(const float* __restrict__ kvf, u16* __restrict__ kvb) {
  const int i = blockIdx.x * 256 + threadIdx.x;  // 262144 = 16*128*128
  const int bhk = i >> 14;
  const int rem = i & 16383;
  const int d = rem >> 7, m = rem & 127;
  kvb[i] = f2b(kvf[(bhk << 14) + m * 128 + d]);
}

extern "C" void kernel_launch(void* const* d_in, const int* in_sizes, int n_in,
                              void* d_out, int out_size, void* d_ws, size_t ws_size,
                              hipStream_t stream)
{
  const float* x  = (const float*)d_in[0];
  const int*   am = (const int*)d_in[1];
  const float* fc = (const float*)d_in[2];
  const float* wq = (const float*)d_in[3];
  const float* wk = (const float*)d_in[4];
  const float* wv = (const float*)d_in[5];
  const float* wo = (const float*)d_in[6];
  const float* gq = (const float*)d_in[7];
  const float* gk = (const float*)d_in[8];
  const float* pj = (const float*)d_in[9];
  float* out = (float*)d_out;

  char* w = (char*)d_ws;
  size_t off = 0;
  u16*   xb    = (u16*)(w + off);  off += (size_t)B_ * S_ * DIM_ * 2;          // 33.5 MB
  u16*   wqkvb = (u16*)(w + off);  off += 4096ull * 2048 * 2;                  // 16.8 MB
  u16*   wob   = (u16*)(w + off);  off += 2048ull * 2048 * 2;                  // 8.4 MB
  float* qkv   = (float*)(w + off); off += (size_t)B_ * S_ * 4096 * 4;        // 134 MB
  float* kpre  = (float*)(w + off); off += (size_t)B_ * HK_ * S_ * M_ * 4;    // 33.5 MB (later qphib)
  u16*   kphiT = (u16*)(w + off);  off += (size_t)B_ * HK_ * S_ * M_ * 2;      // 16.8 MB
  u16*   vT    = (u16*)(w + off);  off += (size_t)B_ * HK_ * S_ * HD_ * 2;     // 16.8 MB
  float* kvf   = (float*)(w + off); off += (size_t)B_ * HK_ * M_ * HD_ * 4;   // 1 MB
  u16*   kvb   = (u16*)(w + off);  off += (size_t)B_ * HK_ * M_ * HD_ * 2;     // 0.5 MB
  float* pT    = (float*)(w + off); off += 128ull * 128 * 4;
  unsigned* kmaxu = (unsigned*)(w + off); off += (size_t)B_ * HK_ * M_ * 4;
  float* ksum  = (float*)(w + off); off += (size_t)B_ * HK_ * M_ * 4;
  float* denom = (float*)(w + off); off += (size_t)B_ * H_ * S_ * 4;
  u16*   attnb = xb;                 // alias: xb dead after QKV GEMM
  u16*   qphib = (u16*)kpre;         // alias: kpre dead after kexp
  if (ws_size < off) return;  // ~263 MB required

  f2b_kernel<<<16384, 256, 0, stream>>>(x, xb, 4194304);
  f2b_kernel<<<4096, 256, 0, stream>>>(wq, wqkvb, 1048576);
  f2b_kernel<<<2048, 256, 0, stream>>>(wk, wqkvb + 4194304, 524288);
  f2b_kernel<<<2048, 256, 0, stream>>>(wv, wqkvb + 6291456, 524288);
  f2b_kernel<<<4096, 256, 0, stream>>>(wo, wob, 1048576);
  tproj_kernel<<<64, 256, 0, stream>>>(pj, pT);
  init_kernel<<<1024, 256, 0, stream>>>(kvf, kmaxu, ksum);

  // QKV projection: [8192,4096] = xb[8192,2048] @ wqkvb[4096,2048]^T  (256² 8-phase)
  gemm256<<<512, 512, 0, stream>>>(xb, wqkvb, qkv, 2048, 4096, 32);

  favor_kernel<0><<<dim3(S_ / 16, HK_, B_), 256, 0, stream>>>(
      qkv, fc, gk, pT, kpre, kmaxu, nullptr, nullptr, nullptr, 2048);
  kexp_kernel<<<dim3(S_ / 64, HK_, B_), 256, 0, stream>>>(kpre, kmaxu, am, kphiT, ksum);
  vT_kernel<<<dim3(S_ / 64, HK_, B_), 256, 0, stream>>>(qkv, am, vT);
  favor_kernel<1><<<dim3(S_ / 16, H_, B_), 256, 0, stream>>>(
      qkv, fc, gq, pT, nullptr, nullptr, qphib, ksum, denom, 0);

  // kv[m,d] = sum_s kphi[s,m] v[s,d] : 16 batches, split-K 16
  gemm_bt<<<dim3(1, 1, 256), 256, 0, stream>>>(kphiT, vT, kvf,
      128, 128, 4096, 524288ull, 524288ull, 16384ull, 0, 128, 16);
  kvb_kernel<<<1024, 256, 0, stream>>>(kvf, kvb);

  // out = qphi @ kv^T, fused denom/mask/bf16/head-transpose epilogue
  gemm_out_epi<<<dim3(32, 1, 32), 256, 0, stream>>>(qphib, kvb, denom, am, attnb);

  // final projection: [8192,2048] = attnb @ wob^T  (256² 8-phase)
  gemm256<<<256, 512, 0, stream>>>(attnb, wob, out, 2048, 2048, 32);
}

// Round 4
// 668.651 us; speedup vs baseline: 1.2496x; 1.0385x over previous
//
#include <hip/hip_runtime.h>

#define B_ 2
#define S_ 4096
#define DIM_ 2048
#define H_ 16
#define HK_ 8
#define HD_ 128
#define M_ 128

typedef unsigned short u16;
typedef __bf16 bf16x8 __attribute__((ext_vector_type(8)));
typedef float f32x4 __attribute__((ext_vector_type(4)));

#define AS1 __attribute__((address_space(1)))
#define AS3 __attribute__((address_space(3)))

__device__ __forceinline__ u16 f2b(float f) {
  unsigned u = __float_as_uint(f);
  u = u + 0x7fffu + ((u >> 16) & 1u);
  return (u16)(u >> 16);
}
__device__ __forceinline__ float b2f(u16 h) {
  return __uint_as_float(((unsigned)h) << 16);
}
__device__ __forceinline__ unsigned fenc(float f) {
  unsigned u = __float_as_uint(f);
  return (u & 0x80000000u) ? ~u : (u | 0x80000000u);
}
__device__ __forceinline__ float fdec(unsigned e) {
  unsigned u = (e & 0x80000000u) ? (e & 0x7fffffffu) : ~e;
  return __uint_as_float(u);
}

// ---------------- fused prep: all f2b converts + proj transpose + inits ----------------
__global__ __launch_bounds__(256) void prep_kernel(
    const float* __restrict__ x, const float* __restrict__ wq,
    const float* __restrict__ wk, const float* __restrict__ wv,
    const float* __restrict__ wo, const float* __restrict__ pj,
    u16* __restrict__ xb, u16* __restrict__ wqkvb, u16* __restrict__ wob,
    float* __restrict__ pT, float* __restrict__ kvf,
    unsigned* __restrict__ kmaxu, float* __restrict__ ksum)
{
  int bid = blockIdx.x;
  const int t = threadIdx.x;
  if (bid < 16384) {                 // x -> xb (4,194,304 float4)
    const int i = bid * 256 + t;
    float4 v = ((const float4*)x)[i];
    ushort4 o; o.x = f2b(v.x); o.y = f2b(v.y); o.z = f2b(v.z); o.w = f2b(v.w);
    ((ushort4*)xb)[i] = o;
    return;
  }
  bid -= 16384;
  if (bid < 4096) {                  // wq -> wqkvb[0]
    const int i = bid * 256 + t;
    float4 v = ((const float4*)wq)[i];
    ushort4 o; o.x = f2b(v.x); o.y = f2b(v.y); o.z = f2b(v.z); o.w = f2b(v.w);
    ((ushort4*)wqkvb)[i] = o;
    return;
  }
  bid -= 4096;
  if (bid < 2048) {                  // wk -> wqkvb + 4,194,304
    const int i = bid * 256 + t;
    float4 v = ((const float4*)wk)[i];
    ushort4 o; o.x = f2b(v.x); o.y = f2b(v.y); o.z = f2b(v.z); o.w = f2b(v.w);
    ((ushort4*)(wqkvb + 4194304))[i] = o;
    return;
  }
  bid -= 2048;
  if (bid < 2048) {                  // wv -> wqkvb + 6,291,456
    const int i = bid * 256 + t;
    float4 v = ((const float4*)wv)[i];
    ushort4 o; o.x = f2b(v.x); o.y = f2b(v.y); o.z = f2b(v.z); o.w = f2b(v.w);
    ((ushort4*)(wqkvb + 6291456))[i] = o;
    return;
  }
  bid -= 2048;
  if (bid < 4096) {                  // wo -> wob
    const int i = bid * 256 + t;
    float4 v = ((const float4*)wo)[i];
    ushort4 o; o.x = f2b(v.x); o.y = f2b(v.y); o.z = f2b(v.z); o.w = f2b(v.w);
    ((ushort4*)wob)[i] = o;
    return;
  }
  bid -= 4096;
  if (bid < 64) {                    // pj -> pT (transpose 128x128)
    const int i = bid * 256 + t;
    pT[i] = pj[(i & 127) * 128 + (i >> 7)];
    return;
  }
  bid -= 64;
  {                                  // init kvf / kmaxu / ksum (1024 blocks)
    const int i = bid * 256 + t;
    if (i < B_ * HK_ * M_ * HD_) kvf[i] = 0.f;
    if (i < B_ * HK_ * M_) { kmaxu[i] = 0u; ksum[i] = 0.f; }
  }
}

// ================= 256x256 8-phase bf16 GEMM, counted-vmcnt ledger =================
// C[M,N] = A[M,K] * B[N,K]^T, fp32 out. 512 thr (8 waves 2Mx4N), BK=64,
// LDS 128KiB (2 dbuf x [A|B]), XOR-swizzle (row&7)<<4 both-sides.
// Staging for tile t+1 split across tile t's 4 phases in consumption order:
//   q0: B sub0, q1: B sub1, q2: A-early(rows 0-63), q3: A-late(rows 64-127).
// Waits: end-q1 vmcnt(4) [drains this tile's A-late], end-q3 vmcnt(2)
// [drains next tile's B+A-early, leaves its A-late in flight]. Never 0 mid-loop.
__global__ __launch_bounds__(512, 2) void gemm256(
    const u16* __restrict__ A, const u16* __restrict__ Bm, float* __restrict__ C,
    int K, int ldc, int nbx)
{
  __shared__ __align__(16) u16 lds[65536];   // 128 KiB
  const int t = threadIdx.x;
  const int wave = t >> 6, lane = t & 63;
  const int nwg = gridDim.x;
  const int q8 = nwg >> 3;
  const int id = blockIdx.x;
  const int sid = (id & 7) * q8 + (id >> 3);      // XCD swizzle (nwg % 8 == 0)
  const int nby = nwg / nbx;
  const int by = sid % nby;
  const int bx = sid / nby;
  const int wave_m = wave >> 2;      // 0..1
  const int wave_n = wave & 3;       // 0..3
  const int lr = lane & 15, lg = lane >> 4;

  const int srow = lane >> 3;                       // row within 8-row octet
  const int scolE = (((lane & 7) ^ srow) << 3);     // pre-swizzled source col (elems)

  const int NT = K >> 6;
  f32x4 acc[8][4] = {};

  const u16* Abase = A + (size_t)bx * 256 * (size_t)K;
  const u16* Bbase = Bm + (size_t)by * 256 * (size_t)K;

  // Stage macros: (buf, k element offset). Per wave: 2 gloads each.
#define STAGE_B(sub, nb, kn)                                                          \
  {                                                                                   \
    _Pragma("unroll")                                                                 \
    for (int hh = 0; hh < 2; hh++)                                                    \
      __builtin_amdgcn_global_load_lds(                                               \
          (const AS1 void*)(Bbase + (size_t)(hh * 128 + (wave * 2 + (sub)) * 8 + srow) * K + (kn) + scolE), \
          (AS3 void*)&lds[32768 + (nb) * 16384 + hh * 8192 + (wave * 2 + (sub)) * 512], 16, 0, 0); \
  }
#define STAGE_AE(nb, kn)                                                              \
  {                                                                                   \
    _Pragma("unroll")                                                                 \
    for (int hh = 0; hh < 2; hh++)                                                    \
      __builtin_amdgcn_global_load_lds(                                               \
          (const AS1 void*)(Abase + (size_t)(hh * 128 + wave * 8 + srow) * K + (kn) + scolE), \
          (AS3 void*)&lds[(nb) * 16384 + hh * 8192 + wave * 512], 16, 0, 0);          \
  }
#define STAGE_AL(nb, kn)                                                              \
  {                                                                                   \
    _Pragma("unroll")                                                                 \
    for (int hh = 0; hh < 2; hh++)                                                    \
      __builtin_amdgcn_global_load_lds(                                               \
          (const AS1 void*)(Abase + (size_t)(hh * 128 + 64 + wave * 8 + srow) * K + (kn) + scolE), \
          (AS3 void*)&lds[(nb) * 16384 + hh * 8192 + (8 + wave) * 512], 16, 0, 0);    \
  }

#define DO_PHASE(mh, nh, STAGE_STMT, PRE_BAR_WAIT)                                    \
  {                                                                                   \
    bf16x8 af[4][2], bv[2][2];                                                        \
    _Pragma("unroll")                                                                 \
    for (int m = 0; m < 4; m++) {                                                     \
      const int r = (mh) * 64 + m * 16 + lr;                                          \
      _Pragma("unroll")                                                               \
      for (int kk = 0; kk < 2; kk++) {                                                \
        const int cb = ((kk << 6) | (lg << 4)) ^ ((lr & 7) << 4);                     \
        af[m][kk] = *(const bf16x8*)&lds[AbaseH + r * 64 + (cb >> 1)];                \
      }                                                                               \
    }                                                                                 \
    _Pragma("unroll")                                                                 \
    for (int n = 0; n < 2; n++) {                                                     \
      const int r = (wave_n & 1) * 64 + (nh) * 32 + n * 16 + lr;                      \
      _Pragma("unroll")                                                               \
      for (int kk = 0; kk < 2; kk++) {                                                \
        const int cb = ((kk << 6) | (lg << 4)) ^ ((lr & 7) << 4);                     \
        bv[n][kk] = *(const bf16x8*)&lds[BbaseH + r * 64 + (cb >> 1)];                \
      }                                                                               \
    }                                                                                 \
    STAGE_STMT;                                                                       \
    asm volatile("" ::: "memory");                                                    \
    __builtin_amdgcn_s_barrier();                                                     \
    asm volatile("" ::: "memory");                                                    \
    __builtin_amdgcn_s_setprio(1);                                                    \
    _Pragma("unroll")                                                                 \
    for (int kk = 0; kk < 2; kk++)                                                    \
      _Pragma("unroll")                                                               \
      for (int m = 0; m < 4; m++)                                                     \
        _Pragma("unroll")                                                             \
        for (int n = 0; n < 2; n++)                                                   \
          acc[(mh) * 4 + m][(nh) * 2 + n] = __builtin_amdgcn_mfma_f32_16x16x32_bf16(  \
              af[m][kk], bv[n][kk], acc[(mh) * 4 + m][(nh) * 2 + n], 0, 0, 0);        \
    __builtin_amdgcn_s_setprio(0);                                                    \
    PRE_BAR_WAIT;                                                                     \
    asm volatile("" ::: "memory");                                                    \
    __builtin_amdgcn_s_barrier();                                                     \
    asm volatile("" ::: "memory");                                                    \
  }

  // prologue: stage tile 0 (order: B, A-early, A-late), wait all but A-late
  STAGE_B(0, 0, 0) STAGE_B(1, 0, 0) STAGE_AE(0, 0) STAGE_AL(0, 0)
  asm volatile("s_waitcnt vmcnt(2)" ::: "memory");
  __builtin_amdgcn_s_barrier();
  asm volatile("" ::: "memory");

  for (int tt = 0; tt < NT; ++tt) {
    const int cur = tt & 1, nxt = cur ^ 1;
    const int kn = (tt + 1) << 6;
    const bool nl = (tt + 1 < NT);
    const int AbaseH = cur * 16384 + wave_m * 8192;
    const int BbaseH = 32768 + cur * 16384 + (wave_n >> 1) * 8192;
    DO_PHASE(0, 0, if (nl) { STAGE_B(0, nxt, kn) }, )
    DO_PHASE(0, 1, if (nl) { STAGE_B(1, nxt, kn) },
             if (nl) { asm volatile("s_waitcnt vmcnt(4)" ::: "memory"); }
             else    { asm volatile("s_waitcnt vmcnt(0)" ::: "memory"); })
    DO_PHASE(1, 0, if (nl) { STAGE_AE(nxt, kn) }, )
    DO_PHASE(1, 1, if (nl) { STAGE_AL(nxt, kn) },
             asm volatile("s_waitcnt vmcnt(2)" ::: "memory");)
  }

  float* Cb = C + (size_t)(bx * 256 + wave_m * 128 + lg * 4) * ldc + by * 256 + wave_n * 64 + lr;
#pragma unroll
  for (int i = 0; i < 8; i++)
#pragma unroll
    for (int j = 0; j < 4; j++)
#pragma unroll
      for (int r = 0; r < 4; r++)
        Cb[(size_t)(i * 16 + r) * ldc + j * 16] = acc[i][j][r];
#undef DO_PHASE
#undef STAGE_B
#undef STAGE_AE
#undef STAGE_AL
}

// ---------------- m97-style bf16 B^T GEMM (kept for the small kv GEMM) ----------------
__global__ __launch_bounds__(256) void gemm_bt(
    const u16* __restrict__ A, const u16* __restrict__ Bm, float* __restrict__ C,
    int M, int N, int K,
    unsigned long long sAb, unsigned long long sBb, unsigned long long sCb,
    int bshiftB, int ldc, int ksplit)
{
  __shared__ __align__(16) u16 sA[128 * 32];
  __shared__ __align__(16) u16 sB[128 * 32];
  const int t = threadIdx.x;
  const int wave = t >> 6, lane = t & 63;
  const int z = blockIdx.z;
  const int batch = z / ksplit;
  const int ks = z - batch * ksplit;
  const int kLen = K / ksplit, kBeg = ks * kLen;

  const u16* Ab = A + (size_t)batch * sAb + (size_t)blockIdx.x * 128 * (size_t)K;
  const u16* Bb = Bm + (size_t)(batch >> bshiftB) * sBb + (size_t)blockIdx.y * 128 * (size_t)K;
  float* Cb = C + (size_t)batch * sCb + (size_t)blockIdx.x * 128 * (size_t)ldc
                + (size_t)blockIdx.y * 128;

  const int r0 = wave * 16 + (lane >> 2);
  const int e0 = (lane & 3) * 8;
  const int wr = wave >> 1, wc = wave & 1;

  f32x4 acc[4][4] = {};

  for (int k0 = kBeg; k0 < kBeg + kLen; k0 += 32) {
#pragma unroll
    for (int i = 0; i < 2; i++) {
      __builtin_amdgcn_global_load_lds(
          (const AS1 void*)(Ab + (size_t)(r0 + i * 64) * K + k0 + e0),
          (AS3 void*)(&sA[(i * 4 + wave) * 512]), 16, 0, 0);
      __builtin_amdgcn_global_load_lds(
          (const AS1 void*)(Bb + (size_t)(r0 + i * 64) * K + k0 + e0),
          (AS3 void*)(&sB[(i * 4 + wave) * 512]), 16, 0, 0);
    }
    __syncthreads();
    bf16x8 av[4], bv[4];
#pragma unroll
    for (int m = 0; m < 4; m++)
      av[m] = *(const bf16x8*)&sA[(wr * 64 + m * 16 + (lane & 15)) * 32 + (lane >> 4) * 8];
#pragma unroll
    for (int n = 0; n < 4; n++)
      bv[n] = *(const bf16x8*)&sB[(wc * 64 + n * 16 + (lane & 15)) * 32 + (lane >> 4) * 8];
#pragma unroll
    for (int m = 0; m < 4; m++)
#pragma unroll
      for (int n = 0; n < 4; n++)
        acc[m][n] = __builtin_amdgcn_mfma_f32_16x16x32_bf16(av[m], bv[n], acc[m][n], 0, 0, 0);
    __syncthreads();
  }

  const int crow0 = wr * 64 + (lane >> 4) * 4;
  const int ccol = wc * 64 + (lane & 15);
  if (ksplit == 1) {
#pragma unroll
    for (int m = 0; m < 4; m++)
#pragma unroll
      for (int n = 0; n < 4; n++)
#pragma unroll
        for (int r = 0; r < 4; r++)
          Cb[(size_t)(crow0 + m * 16 + r) * ldc + ccol + n * 16] = acc[m][n][r];
  } else {
#pragma unroll
    for (int m = 0; m < 4; m++)
#pragma unroll
      for (int n = 0; n < 4; n++)
#pragma unroll
        for (int r = 0; r < 4; r++)
          atomicAdd(&Cb[(size_t)(crow0 + m * 16 + r) * ldc + ccol + n * 16], acc[m][n][r]);
  }
}

// ---------------- out = qphi @ kv^T with fused denom/mask/bf16/head-transpose ----------------
__global__ __launch_bounds__(256) void gemm_out_epi(
    const u16* __restrict__ qphib, const u16* __restrict__ kvb,
    const float* __restrict__ denom, const int* __restrict__ amask,
    u16* __restrict__ attnb)
{
  __shared__ __align__(16) u16 sA[128 * 32];
  __shared__ __align__(16) u16 sB[128 * 32];
  const int t = threadIdx.x;
  const int wave = t >> 6, lane = t & 63;
  const int batch = blockIdx.z;           // b*16 + h
  const int b = batch >> 4, h = batch & 15;

  const u16* Ab = qphib + (size_t)batch * 524288 + (size_t)blockIdx.x * 128 * 128;
  const u16* Bb = kvb + (size_t)(batch >> 1) * 16384;

  const int r0 = wave * 16 + (lane >> 2);
  const int e0 = (lane & 3) * 8;
  const int wr = wave >> 1, wc = wave & 1;

  f32x4 acc[4][4] = {};

  for (int k0 = 0; k0 < 128; k0 += 32) {
#pragma unroll
    for (int i = 0; i < 2; i++) {
      __builtin_amdgcn_global_load_lds(
          (const AS1 void*)(Ab + (size_t)(r0 + i * 64) * 128 + k0 + e0),
          (AS3 void*)(&sA[(i * 4 + wave) * 512]), 16, 0, 0);
      __builtin_amdgcn_global_load_lds(
          (const AS1 void*)(Bb + (size_t)(r0 + i * 64) * 128 + k0 + e0),
          (AS3 void*)(&sB[(i * 4 + wave) * 512]), 16, 0, 0);
    }
    __syncthreads();
    bf16x8 av[4], bv[4];
#pragma unroll
    for (int m = 0; m < 4; m++)
      av[m] = *(const bf16x8*)&sA[(wr * 64 + m * 16 + (lane & 15)) * 32 + (lane >> 4) * 8];
#pragma unroll
    for (int n = 0; n < 4; n++)
      bv[n] = *(const bf16x8*)&sB[(wc * 64 + n * 16 + (lane & 15)) * 32 + (lane >> 4) * 8];
#pragma unroll
    for (int m = 0; m < 4; m++)
#pragma unroll
      for (int n = 0; n < 4; n++)
        acc[m][n] = __builtin_amdgcn_mfma_f32_16x16x32_bf16(av[m], bv[n], acc[m][n], 0, 0, 0);
    __syncthreads();
  }

  const int crow0 = wr * 64 + (lane >> 4) * 4;
  const int ccol = wc * 64 + (lane & 15);
#pragma unroll
  for (int m = 0; m < 4; m++)
#pragma unroll
    for (int r = 0; r < 4; r++) {
      const int s = blockIdx.x * 128 + crow0 + m * 16 + r;
      const float inv = (amask[b * S_ + s] > 0)
                          ? 1.f / (denom[(size_t)batch * S_ + s] + 1e-6f) : 0.f;
      u16* orow = attnb + ((size_t)(b * S_ + s)) * 2048 + h * 128 + ccol;
#pragma unroll
      for (int n = 0; n < 4; n++)
        orow[n * 16] = f2b(acc[m][n][r] * inv);
    }
}

// ---------------- RMSNorm + RoPE + FAVOR features (fp32) ----------------
template <int IS_Q>
__global__ __launch_bounds__(256) void favor_kernel(
    const float* __restrict__ qkv, const float* __restrict__ fc,
    const float* __restrict__ g, const float* __restrict__ pT,
    float* __restrict__ kpre, unsigned* __restrict__ kmaxu,
    u16* __restrict__ qphib, const float* __restrict__ ksum, float* __restrict__ denom,
    int colbase)
{
  const int b = blockIdx.z, h = blockIdx.y;
  const int wave = threadIdx.x >> 6, lane = threadIdx.x & 63;
  const int s0 = blockIdx.x * 16 + wave * 4;
  __shared__ float xs[4][4][128];
  __shared__ float sm[4][128];
  float halfss[4];
  const int col = colbase + h * HD_;

#pragma unroll
  for (int tt = 0; tt < 4; tt++) {
    const int s = s0 + tt;
    const size_t row = (size_t)b * S_ + s;
    const float* xr = qkv + row * 4096 + col;
    float a = xr[2 * lane], bb = xr[2 * lane + 1];
    float ss = a * a + bb * bb;
#pragma unroll
    for (int o = 1; o < 64; o <<= 1) ss += __shfl_xor(ss, o);
    const float sc = rsqrtf(ss * (1.f / HD_) + 1e-5f);
    a *= sc * g[2 * lane];
    bb *= sc * g[2 * lane + 1];
    const float2 cs = *(const float2*)&fc[(row * 64 + lane) * 2];
    float na = a * cs.x - bb * cs.y;
    float nb = a * cs.y + bb * cs.x;
    na *= 0.29730177875068026f;   // 128^-0.25
    nb *= 0.29730177875068026f;
    xs[wave][tt][2 * lane] = na;
    xs[wave][tt][2 * lane + 1] = nb;
    float s2 = na * na + nb * nb;
#pragma unroll
    for (int o = 1; o < 64; o <<= 1) s2 += __shfl_xor(s2, o);
    halfss[tt] = 0.5f * s2;
  }

  float acc[4][2] = {};
  for (int d = 0; d < 128; d++) {
    const float2 p = *(const float2*)&pT[d * 128 + 2 * lane];
#pragma unroll
    for (int tt = 0; tt < 4; tt++) {
      const float xv = xs[wave][tt][d];
      acc[tt][0] = fmaf(p.x, xv, acc[tt][0]);
      acc[tt][1] = fmaf(p.y, xv, acc[tt][1]);
    }
  }

  if (IS_Q) {
#pragma unroll
    for (int tt = 0; tt < 4; tt++) {
      const int s = s0 + tt;
      const float p0 = acc[tt][0] - halfss[tt], p1 = acc[tt][1] - halfss[tt];
      float mx = fmaxf(p0, p1);
#pragma unroll
      for (int o = 1; o < 64; o <<= 1) mx = fmaxf(mx, __shfl_xor(mx, o));
      const float f0 = expf(p0 - mx) * 0.08838834764831845f + 1e-6f;  // M^-0.5
      const float f1 = expf(p1 - mx) * 0.08838834764831845f + 1e-6f;
      const u16 u0 = f2b(f0), u1 = f2b(f1);
      const size_t base = (((size_t)(b * H_ + h)) * S_ + s) * M_;
      ushort2 st2; st2.x = u0; st2.y = u1;
      *(ushort2*)&qphib[base + 2 * lane] = st2;
      const float* ksb = ksum + ((b * HK_) + (h >> 1)) * M_;
      float dsum = b2f(u0) * ksb[2 * lane] + b2f(u1) * ksb[2 * lane + 1];
#pragma unroll
      for (int o = 1; o < 64; o <<= 1) dsum += __shfl_xor(dsum, o);
      if (lane == 0) denom[((size_t)(b * H_ + h)) * S_ + s] = dsum;
    }
  } else {
    float mx0 = -1e30f, mx1 = -1e30f;
#pragma unroll
    for (int tt = 0; tt < 4; tt++) {
      const int s = s0 + tt;
      const float p0 = acc[tt][0] - halfss[tt], p1 = acc[tt][1] - halfss[tt];
      const size_t base = (((size_t)(b * HK_ + h)) * S_ + s) * M_;
      float2 w2; w2.x = p0; w2.y = p1;
      *(float2*)&kpre[base + 2 * lane] = w2;
      mx0 = fmaxf(mx0, p0);
      mx1 = fmaxf(mx1, p1);
    }
    sm[wave][2 * lane] = mx0;
    sm[wave][2 * lane + 1] = mx1;
    __syncthreads();
    if (threadIdx.x < 128) {
      const float v = fmaxf(fmaxf(sm[0][threadIdx.x], sm[1][threadIdx.x]),
                            fmaxf(sm[2][threadIdx.x], sm[3][threadIdx.x]));
      atomicMax(&kmaxu[(b * HK_ + h) * M_ + threadIdx.x], fenc(v));
    }
  }
}

// ---------------- k-side: exp(pre - max), mask, transpose to [m][s], k_sum ----------------
__global__ __launch_bounds__(256) void kexp_kernel(
    const float* __restrict__ kpre, const unsigned* __restrict__ kmaxu,
    const int* __restrict__ amask, u16* __restrict__ kphiT, float* __restrict__ ksum)
{
  const int b = blockIdx.z, hk = blockIdx.y;
  const int c0 = blockIdx.x * 64;
  const int t = threadIdx.x;
  const int m = t & 127, half = t >> 7;
  __shared__ __align__(16) u16 st[128][64];
  __shared__ float red[256];
  const int bhk = b * HK_ + hk;
  const float kmax = fdec(kmaxu[bhk * M_ + m]);
  float sum = 0.f;
  const int msw = (m & 7) << 3;
  for (int i = 0; i < 32; i++) {
    const int sl = half * 32 + i;
    const int s = c0 + sl;
    const float pre = kpre[(((size_t)bhk) * S_ + s) * M_ + m];
    const int va = amask[b * S_ + s] > 0;
    const float phi = va ? (expf(pre - kmax) * 0.08838834764831845f + 1e-6f) : 0.f;
    sum += phi;
    st[m][sl ^ msw] = f2b(phi);
  }
  red[t] = sum;
  __syncthreads();
  if (t < 128) atomicAdd(&ksum[bhk * M_ + t], red[t] + red[t + 128]);
  const int mr = t >> 1, part = t & 1;
  const int rsw = (mr & 7) << 3;
  const size_t base = ((size_t)(bhk * M_ + mr)) * S_ + c0 + part * 32;
#pragma unroll
  for (int k = 0; k < 4; k++)
    *(uint4*)&kphiT[base + k * 8] = *(const uint4*)&st[mr][(part * 32 + k * 8) ^ rsw];
}

// ---------------- v: mask + bf16 + transpose to [d][s] ----------------
__global__ __launch_bounds__(256) void vT_kernel(
    const float* __restrict__ qkv, const int* __restrict__ amask, u16* __restrict__ vT)
{
  const int b = blockIdx.z, hk = blockIdx.y;
  const int c0 = blockIdx.x * 64;
  const int t = threadIdx.x;
  const int d = t & 127, half = t >> 7;
  __shared__ __align__(16) u16 st[128][64];
  const int bhk = b * HK_ + hk;
  const int dsw = (d & 7) << 3;
  for (int i = 0; i < 32; i++) {
    const int sl = half * 32 + i;
    const int s = c0 + sl;
    const float v = qkv[((size_t)(b * S_ + s)) * 4096 + 3072 + hk * 128 + d];
    const int va = amask[b * S_ + s] > 0;
    st[d][sl ^ dsw] = f2b(va ? v : 0.f);
  }
  __syncthreads();
  const int dr = t >> 1, part = t & 1;
  const int rsw = (dr & 7) << 3;
  const size_t base = ((size_t)(bhk * 128 + dr)) * S_ + c0 + part * 32;
#pragma unroll
  for (int k = 0; k < 4; k++)
    *(uint4*)&vT[base + k * 8] = *(const uint4*)&st[dr][(part * 32 + k * 8) ^ rsw];
}

// ---------------- kv fp32 -> bf16, transpose [m][d] -> [d][m] ----------------
__global__ void kvb_kernel(const float* __restrict__ kvf, u16* __restrict__ kvb) {
  const int i = blockIdx.x * 256 + threadIdx.x;  // 262144 = 16*128*128
  const int bhk = i >> 14;
  const int rem = i & 16383;
  const int d = rem >> 7, m = rem & 127;
  kvb[i] = f2b(kvf[(bhk << 14) + m * 128 + d]);
}

extern "C" void kernel_launch(void* const* d_in, const int* in_sizes, int n_in,
                              void* d_out, int out_size, void* d_ws, size_t ws_size,
                              hipStream_t stream)
{
  const float* x  = (const float*)d_in[0];
  const int*   am = (const int*)d_in[1];
  const float* fc = (const float*)d_in[2];
  const float* wq = (const float*)d_in[3];
  const float* wk = (const float*)d_in[4];
  const float* wv = (const float*)d_in[5];
  const float* wo = (const float*)d_in[6];
  const float* gq = (const float*)d_in[7];
  const float* gk = (const float*)d_in[8];
  const float* pj = (const float*)d_in[9];
  float* out = (float*)d_out;

  char* w = (char*)d_ws;
  size_t off = 0;
  u16*   xb    = (u16*)(w + off);  off += (size_t)B_ * S_ * DIM_ * 2;          // 33.5 MB
  u16*   wqkvb = (u16*)(w + off);  off += 4096ull * 2048 * 2;                  // 16.8 MB
  u16*   wob   = (u16*)(w + off);  off += 2048ull * 2048 * 2;                  // 8.4 MB
  float* qkv   = (float*)(w + off); off += (size_t)B_ * S_ * 4096 * 4;        // 134 MB
  float* kpre  = (float*)(w + off); off += (size_t)B_ * HK_ * S_ * M_ * 4;    // 33.5 MB (later qphib)
  u16*   kphiT = (u16*)(w + off);  off += (size_t)B_ * HK_ * S_ * M_ * 2;      // 16.8 MB
  u16*   vT    = (u16*)(w + off);  off += (size_t)B_ * HK_ * S_ * HD_ * 2;     // 16.8 MB
  float* kvf   = (float*)(w + off); off += (size_t)B_ * HK_ * M_ * HD_ * 4;   // 1 MB
  u16*   kvb   = (u16*)(w + off);  off += (size_t)B_ * HK_ * M_ * HD_ * 2;     // 0.5 MB
  float* pT    = (float*)(w + off); off += 128ull * 128 * 4;
  unsigned* kmaxu = (unsigned*)(w + off); off += (size_t)B_ * HK_ * M_ * 4;
  float* ksum  = (float*)(w + off); off += (size_t)B_ * HK_ * M_ * 4;
  float* denom = (float*)(w + off); off += (size_t)B_ * H_ * S_ * 4;
  u16*   attnb = xb;                 // alias: xb dead after QKV GEMM
  u16*   qphib = (u16*)kpre;         // alias: kpre dead after kexp
  if (ws_size < off) return;  // ~263 MB required

  // fused converts + transposes + inits (one launch)
  prep_kernel<<<29760, 256, 0, stream>>>(x, wq, wk, wv, wo, pj,
                                         xb, wqkvb, wob, pT, kvf, kmaxu, ksum);

  // QKV projection: [8192,4096] = xb[8192,2048] @ wqkvb[4096,2048]^T
  gemm256<<<512, 512, 0, stream>>>(xb, wqkvb, qkv, 2048, 4096, 32);

  favor_kernel<0><<<dim3(S_ / 16, HK_, B_), 256, 0, stream>>>(
      qkv, fc, gk, pT, kpre, kmaxu, nullptr, nullptr, nullptr, 2048);
  kexp_kernel<<<dim3(S_ / 64, HK_, B_), 256, 0, stream>>>(kpre, kmaxu, am, kphiT, ksum);
  vT_kernel<<<dim3(S_ / 64, HK_, B_), 256, 0, stream>>>(qkv, am, vT);
  favor_kernel<1><<<dim3(S_ / 16, H_, B_), 256, 0, stream>>>(
      qkv, fc, gq, pT, nullptr, nullptr, qphib, ksum, denom, 0);

  // kv[m,d] = sum_s kphi[s,m] v[s,d] : 16 batches, split-K 16
  gemm_bt<<<dim3(1, 1, 256), 256, 0, stream>>>(kphiT, vT, kvf,
      128, 128, 4096, 524288ull, 524288ull, 16384ull, 0, 128, 16);
  kvb_kernel<<<1024, 256, 0, stream>>>(kvf, kvb);

  // out = qphi @ kv^T, fused denom/mask/bf16/head-transpose epilogue
  gemm_out_epi<<<dim3(32, 1, 32), 256, 0, stream>>>(qphib, kvb, denom, am, attnb);

  // final projection: [8192,2048] = attnb @ wob^T
  gemm256<<<256, 512, 0, stream>>>(attnb, wob, out, 2048, 2048, 32);
}